// Round 3
// baseline (69.876 us; speedup 1.0000x reference)
//
#include <hip/hip_runtime.h>

// ARIMA(P=16, D=1, Q=16), S0 = 1048577, S = 1048576 diffed samples.
// Output: mean(err^2), one float.
//
// R13: WCHUNK 256 -> 512 (runs of 11, WTILE=704, NBLK=512 = exactly
// 2 blocks/CU, 8 waves/CU). Rationale: R12 counters bound k_arima at
// ~23 us vs a 6-7 us pipe model (VALU 3.7, LDS 5.3) -> the kernel is
// issue/latency-inefficient, not pipe-saturated; wall tracks per-output
// work. Halving the halo+warmup redundancy (1.75x -> 1.375x) and
// amortizing square17 over 2x outputs cuts per-output work ~0.6x.
// Bank strides stay <=2 lanes/bank (runs of 11: gcd(11,32)=1; stride-2:
// 22k mod 32 even 2x + parity; stride-4: 44q mod 32 covers 8 values x2
// + (lane&3)). IIR warmup margin unchanged (9 substeps = 72 samples,
// pole bound lam<=0.89 -> lam^72 <= 2e-4, R9/R10).
//
// R12 (kept): per-block plain store to d_ws[bid] + 1-block k_finish
// (replaced the serialized same-address atomic tail, -5.2 us measured).
//
// Wave-autonomous: wave w of block b owns outputs [wbase, wbase+512),
// wbase = (4b+w)*512; 2048 waves = 512 blocks, no tail. Private LDS
// slice (2 x 792 floats): stage series (float4) -> diff+AR u0
// (head-folded) -> 3 even-odd squaring levels (strides 1,2,4; halo 112)
// -> stride-8 order-16 IIR (9 warmup + 8 output substeps per lane)
// -> wave shfl-reduce -> block combine -> ONE plain store per block.
//
// __launch_bounds__(256,2): occupancy is grid-capped at 2 blocks/CU,
// so the register allocator may use up to 256 VGPR without cost.

#define S_TOTAL 1048576
#define WCHUNK  512
#define NBLK    512                  // 4 waves/block -> 2048 waves, no tail
#define WLOOK   192                  // halo 112 + IIR warmup 72 + slack 8
#define WTILE   704                  // 64 runs of 11 at strides 1,2,4
#define RUN     11
#define SER     724                  // staged series floats (181 float4)
#define GUARD   64                   // zero guard: deepest stage read is -64
#define BUFW    (GUARD + SER + 4)    // 792 floats (3168 B, 16B-aligned rows)

__device__ __forceinline__ void wbar() { __builtin_amdgcn_wave_barrier(); }

// per-thread even-odd squaring: cc <- coeffs of A(z)A(-z) in z^2 (cc[0]==1)
__device__ __forceinline__ void square17(float (&cc)[17])
{
    float b[17];
    #pragma unroll
    for (int m = 0; m <= 16; ++m) {
        float s = 0.0f;
        #pragma unroll
        for (int i = 0; i <= 16; ++i) {
            int j = 2 * m - i;        // i+j even -> (-1)^j == (-1)^i
            if (j >= 0 && j <= 16) {
                float t = cc[i] * cc[j];
                s = (i & 1) ? s - t : s + t;
            }
        }
        b[m] = s;
    }
    #pragma unroll
    for (int m = 0; m <= 16; ++m) cc[m] = b[m];
}

// one level: out[k] = sum_j (-1)^j cc[j] * in[k - j*S], k in [0, WTILE)
// exactly 64 runs of 11 -> lane == run, no loop, no bounds check
template <int LOG_S>
__device__ __forceinline__ void stageW(const float* in, float* out,
                                       const float (&cc)[17], int lane)
{
    constexpr int S = 1 << LOG_S;
    wbar();
    const int ob = (lane & (S - 1)) + RUN * S * (lane >> LOG_S);
    float x[16 + RUN];
    #pragma unroll
    for (int m = 0; m < 16 + RUN; ++m)
        x[m] = in[GUARD + ob + S * (m - 16)];
    #pragma unroll
    for (int i = 0; i < RUN; ++i) {
        float acc = x[16 + i];                    // j=0: cc[0] == 1
        #pragma unroll
        for (int j = 1; j <= 16; ++j) {
            float v = x[16 + i - j];
            acc = (j & 1) ? fmaf(-cc[j], v, acc)  // free VOP3 negate
                          : fmaf(cc[j], v, acc);
        }
        out[GUARD + ob + S * i] = acc;
    }
    wbar();
}

__global__ __launch_bounds__(256, 2) void k_arima(const float* __restrict__ series,
                                                  const float* __restrict__ w_ar,
                                                  const float* __restrict__ w_ma,
                                                  float* __restrict__ partials,
                                                  float* __restrict__ out)
{
    __shared__ __align__(16) float buf[8][BUFW];
    __shared__ float redLDS[4];

    const int tid  = threadIdx.x;
    const int w    = tid >> 6;        // wave 0..3
    const int lane = tid & 63;

    float* bufA = buf[2 * w];
    float* bufB = buf[2 * w + 1];

    const int wbase = (blockIdx.x * 4 + w) * WCHUNK;   // first output t
    const int T0    = wbase - WLOOK;                   // t of u-tile idx 0
    const int gbase = T0 - 16;                         // series idx of elem 0

    // zero guards, both buffers (GUARD == 64 == wave width)
    bufA[lane] = 0.0f;
    bufB[lane] = 0.0f;

    // stage series: bufA[GUARD + i] = series[gbase + i], i in [0, SER)
    if (gbase >= 0 && gbase + SER <= S_TOTAL + 1) {    // gbase % 4 == 0
        const float4* gp = (const float4*)(series + gbase);
        float4* lp = (float4*)(bufA + GUARD);
        lp[lane]      = gp[lane];
        lp[64 + lane] = gp[64 + lane];
        if (lane < SER / 4 - 128) lp[128 + lane] = gp[128 + lane]; // 53 lanes
    } else {   // block 0 wave 0, last wave: clamp (y==0 beyond both ends)
        for (int i = lane; i < SER; i += 64) {
            int g = gbase + i;
            g = min(max(g, 0), S_TOTAL);
            bufA[GUARD + i] = series[g];
        }
    }

    // per-thread coefficient registers (w_ar/w_ma uniform -> s_load)
    float cc[17];
    cc[0] = 1.0f;
    #pragma unroll
    for (int m = 1; m <= 16; ++m) cc[m] = w_ma[16 - m];   // a_m

    wbar();   // staging visible to the wave's own lanes (in-order LDS pipe)

    // u0: diff + AR FIR + head fold (bufA series -> bufB), 64 runs of 11
    {
        const int o0 = RUN * lane;
        float s[17 + RUN], y[16 + RUN];
        #pragma unroll
        for (int m = 0; m < 17 + RUN; ++m) s[m] = bufA[GUARD + o0 + m];
        #pragma unroll
        for (int m = 0; m < 16 + RUN; ++m) y[m] = s[m + 1] - s[m];
        #pragma unroll
        for (int i = 0; i < RUN; ++i) {
            float acc = y[16 + i];                    // j=0 tap == 1
            #pragma unroll
            for (int j = 1; j <= 16; ++j)
                acc = fmaf(-w_ar[16 - j], y[16 + i - j], acc);
            if (T0 < 17) {             // block 0 wave 0 only (uniform)
                int t = T0 + o0 + i;
                if (t <= 16) {
                    acc = 0.0f;        // t<=0 -> 0 (e0 added at the end)
                    if (t >= 1) {      // u = y_t + sum_{j<t} a_j y_{t-j}
                        acc = y[16 + i];
                        for (int j = 1; j < t; ++j)
                            acc += w_ma[16 - j] * y[16 + i - j];
                    }
                }
            }
            bufB[GUARD + o0 + i] = acc;
        }
    }

    // 3 squaring levels (wave-fenced, no block barriers)
    stageW<0>(bufB, bufA, cc, lane);  square17(cc);
    stageW<1>(bufA, bufB, cc, lane);  square17(cc);
    stageW<2>(bufB, bufA, cc, lane);  square17(cc);   // cc = c3 now
    // u3 in bufA; valid for tile idx >= 112

    // stride-8 order-16 IIR: lane = residue rr (0..7) x group g (0..7);
    // group g owns output substeps k in [24+8g, 24+8g+8); 9 warmup substeps
    // before that. warmup start tile idx = 120 + rr + 64g >= 112 ✓
    float acc = 0.0f;
    {
        const int rr   = lane & 7;
        const int g    = lane >> 3;
        const int base = GUARD + WLOOK - 72 + rr + 64 * g;
        float h[16];
        #pragma unroll
        for (int j = 0; j < 16; ++j) h[j] = 0.0f;
        #pragma unroll
        for (int s = 0; s < 17; ++s) {
            float e = bufA[base + 8 * s];
            #pragma unroll
            for (int j = 0; j < 16; ++j) e = fmaf(-cc[j + 1], h[j], e);
            #pragma unroll
            for (int j = 15; j >= 1; --j) h[j] = h[j - 1];
            h[0] = e;
            if (s >= 9) acc += e * e;
        }
    }

    // wave reduce -> block combine (the ONLY __syncthreads) -> ONE plain store
    #pragma unroll
    for (int off = 32; off > 0; off >>= 1)
        acc += __shfl_down(acc, off, 64);
    if (lane == 0) redLDS[w] = acc;
    __syncthreads();
    if (tid == 0) {
        float tot = redLDS[0] + redLDS[1] + redLDS[2] + redLDS[3];
        if (partials) {
            // uncontended: each block owns its slot; k_finish sums them.
            partials[blockIdx.x] = tot;
        } else {
            // fallback (tiny ws): old single-atomic path onto 0xAA poison
            if (blockIdx.x == 0) {
                float y0 = series[1] - series[0];
                tot += y0 * y0;
            }
            atomicAdd(out, tot * (1.0f / (float)S_TOTAL));
        }
    }
}

// 1-block fan-in: 256 threads x float2 = 512 partials; clean store to out.
__global__ __launch_bounds__(256, 1) void k_finish(const float* __restrict__ partials,
                                                   const float* __restrict__ series,
                                                   float* __restrict__ out)
{
    __shared__ float red[4];
    const int tid = threadIdx.x;
    const float2 v = ((const float2*)partials)[tid];
    float s = v.x + v.y;
    #pragma unroll
    for (int off = 32; off > 0; off >>= 1)
        s += __shfl_down(s, off, 64);
    if ((tid & 63) == 0) red[tid >> 6] = s;
    __syncthreads();
    if (tid == 0) {
        float y0 = series[1] - series[0];          // err_0 = y_0
        float tot = red[0] + red[1] + red[2] + red[3] + y0 * y0;
        out[0] = tot * (1.0f / (float)S_TOTAL);    // overwrite poison cleanly
    }
}

extern "C" void kernel_launch(void* const* d_in, const int* in_sizes, int n_in,
                              void* d_out, int out_size, void* d_ws, size_t ws_size,
                              hipStream_t stream) {
    const float* series = (const float*)d_in[0];
    const float* w_ar   = (const float*)d_in[1];
    const float* w_ma   = (const float*)d_in[2];
    float* out = (float*)d_out;

    float* partials = (d_ws && ws_size >= NBLK * sizeof(float)) ? (float*)d_ws
                                                                : nullptr;

    k_arima<<<NBLK, 256, 0, stream>>>(series, w_ar, w_ma, partials, out);
    if (partials)
        k_finish<<<1, 256, 0, stream>>>(partials, series, out);
}